// Round 1
// baseline (1304.346 us; speedup 1.0000x reference)
//
#include <hip/hip_runtime.h>
#include <hip/hip_bf16.h>

#define N_NODES 100000
#define N_EDGES 1600000
#define ET      (N_EDGES + N_NODES)   // edges + self-loops
#define N_GRAPH 512
#define DIN 100
#define DOUT 200
#define HID 400

#define NSLICE 4
#define DSL 25            // DIN / NSLICE
#define CHUNKS 192        // CHUNKS*NSLICE = 768 blocks = 3/CU * 256 CU

// ---------------- init: deg=1 (self-loop), cnt=0, accg=0 ----------------
__global__ void init_kernel(float* deg, float* cnt, float* accg) {
    int i = blockIdx.x * blockDim.x + threadIdx.x;
    if (i < N_NODES) deg[i] = 1.0f;
    if (i < N_GRAPH) cnt[i] = 0.0f;
    if (i < N_GRAPH * DIN) accg[i] = 0.0f;
}

// ---------------- degree count over real edges ----------------
__global__ void deg_kernel(const int* __restrict__ dst, float* __restrict__ deg) {
    int i = blockIdx.x * blockDim.x + threadIdx.x;
    if (i < N_EDGES) atomicAdd(&deg[dst[i]], 1.0f);
}

// ---------------- dinv = rsqrt(deg); per-graph node counts ----------------
__global__ void dinv_kernel(const float* __restrict__ deg, float* __restrict__ dinv,
                            const int* __restrict__ batch, float* __restrict__ cnt) {
    int i = blockIdx.x * blockDim.x + threadIdx.x;
    if (i < N_NODES) {
        float d = deg[i];
        dinv[i] = d > 0.0f ? rsqrtf(d) : 0.0f;
        atomicAdd(&cnt[batch[i]], 1.0f);
    }
}

// ---------------- precompute per-edge weight + group ----------------
__global__ void wg_kernel(const int* __restrict__ ei, const float* __restrict__ dinv,
                          const int* __restrict__ batch,
                          float* __restrict__ we, int* __restrict__ ge) {
    int e = blockIdx.x * blockDim.x + threadIdx.x;
    if (e >= ET) return;
    int s, t;
    if (e < N_EDGES) { s = ei[e]; t = ei[N_EDGES + e]; }
    else             { s = e - N_EDGES; t = s; }
    we[e] = dinv[s] * dinv[t];
    ge[e] = batch[t];
}

// ---------------- main scatter: accg[g][d] += w_e * x[src_e][d] ----------------
template<int USE_WG>
__global__ __launch_bounds__(256)
void scatter_kernel(const float* __restrict__ x, const int* __restrict__ ei,
                    const int* __restrict__ batch, const float* __restrict__ dinv,
                    const float* __restrict__ we, const int* __restrict__ ge,
                    float* __restrict__ accg) {
    __shared__ float lacc[N_GRAPH * DSL];   // 51200 B
    const int tid = threadIdx.x;
    for (int i = tid; i < N_GRAPH * DSL; i += 256) lacc[i] = 0.0f;
    __syncthreads();

    const int slice = blockIdx.y;
    const int doff  = slice * DSL;
    const int per   = (ET + CHUNKS - 1) / CHUNKS;
    const int e0    = blockIdx.x * per;
    const int e1    = (e0 + per < ET) ? (e0 + per) : ET;
    const int grp   = tid >> 5;          // 8 groups of 32 lanes
    const int lane  = tid & 31;
    const bool lact = lane < DSL;

    for (int base = e0 + grp * 4; base < e1; base += 8 * 4) {
        #pragma unroll
        for (int u = 0; u < 4; ++u) {
            int e = base + u;
            if (e < e1) {
                int s;
                float w;
                int g;
                if (USE_WG) {
                    s = (e < N_EDGES) ? ei[e] : (e - N_EDGES);
                    w = we[e];
                    g = ge[e];
                } else {
                    int t;
                    if (e < N_EDGES) { s = ei[e]; t = ei[N_EDGES + e]; }
                    else             { s = e - N_EDGES; t = s; }
                    w = dinv[s] * dinv[t];
                    g = batch[t];
                }
                if (lact) {
                    float xv = x[s * DIN + doff + lane];
                    atomicAdd(&lacc[g * DSL + lane], w * xv);
                }
            }
        }
    }
    __syncthreads();
    for (int i = tid; i < N_GRAPH * DSL; i += 256) {
        int g = i / DSL;
        int d = i - g * DSL;
        atomicAdd(&accg[g * DIN + doff + d], lacc[i]);
    }
}

// ---------------- pooled[g][j] = cnt[g]*b[j] + sum_d accg[g][d]*W[d][j] ----------------
__global__ void pooled_kernel(const float* __restrict__ accg, const float* __restrict__ W,
                              const float* __restrict__ b, const float* __restrict__ cnt,
                              float* __restrict__ pooled) {
    int i = blockIdx.x * blockDim.x + threadIdx.x;
    if (i >= N_GRAPH * DOUT) return;
    int g = i / DOUT, j = i - g * DOUT;
    const float* ar = accg + g * DIN;
    float p = cnt[g] * b[j];
    #pragma unroll 4
    for (int d = 0; d < DIN; ++d) p += ar[d] * W[d * DOUT + j];
    pooled[i] = p;
}

// ---------------- dense (+ ReLU) ----------------
template<int K, int M, bool RELU>
__global__ void mlp_kernel(const float* __restrict__ in, const float* __restrict__ Wt,
                           const float* __restrict__ bias, float* __restrict__ out) {
    int i = blockIdx.x * blockDim.x + threadIdx.x;
    if (i >= N_GRAPH * M) return;
    int g = i / M, m = i - g * M;
    const float* ir = in + g * K;
    float p = bias[m];
    #pragma unroll 4
    for (int k = 0; k < K; ++k) p += ir[k] * Wt[k * M + m];
    out[i] = RELU ? fmaxf(p, 0.0f) : p;
}

// ---------------- head: logits + softmax ----------------
__global__ void head_kernel(const float* __restrict__ z2, const float* __restrict__ Wc,
                            const float* __restrict__ bc, float* __restrict__ out) {
    int g = blockIdx.x * blockDim.x + threadIdx.x;
    if (g >= N_GRAPH) return;
    const float* zr = z2 + g * HID;
    float a0 = bc[0], a1 = bc[1];
    #pragma unroll 4
    for (int k = 0; k < HID; ++k) {
        float z = zr[k];
        a0 += z * Wc[2 * k];
        a1 += z * Wc[2 * k + 1];
    }
    float m = fmaxf(a0, a1);
    float e0 = expf(a0 - m), e1 = expf(a1 - m);
    float s = e0 + e1;
    out[2 * g]     = e0 / s;
    out[2 * g + 1] = e1 / s;
}

extern "C" void kernel_launch(void* const* d_in, const int* in_sizes, int n_in,
                              void* d_out, int out_size, void* d_ws, size_t ws_size,
                              hipStream_t stream) {
    const float* x  = (const float*)d_in[0];
    const float* W  = (const float*)d_in[1];
    const float* b  = (const float*)d_in[2];
    const float* W1 = (const float*)d_in[3];
    const float* b1 = (const float*)d_in[4];
    const float* W2 = (const float*)d_in[5];
    const float* b2 = (const float*)d_in[6];
    const float* Wc = (const float*)d_in[7];
    const float* bc = (const float*)d_in[8];
    const int*   ei = (const int*)d_in[9];
    const int* batch = (const int*)d_in[10];
    float* out = (float*)d_out;

    float* ws = (float*)d_ws;
    float* deg    = ws;            ws += N_NODES;
    float* dinv   = ws;            ws += N_NODES;
    float* cnt    = ws;            ws += N_GRAPH;
    float* accg   = ws;            ws += N_GRAPH * DIN;
    float* pooled = ws;            ws += N_GRAPH * DOUT;
    float* z1     = ws;            ws += N_GRAPH * HID;
    float* z2     = ws;            ws += N_GRAPH * HID;
    float* we     = ws;            ws += ET;
    int*   ge     = (int*)ws;      ws += ET;
    size_t need = (size_t)((float*)ws - (float*)d_ws) * sizeof(float);
    bool use_wg = ws_size >= need;

    init_kernel<<<(N_NODES + 255) / 256, 256, 0, stream>>>(deg, cnt, accg);
    deg_kernel<<<(N_EDGES + 255) / 256, 256, 0, stream>>>(ei + N_EDGES, deg);
    dinv_kernel<<<(N_NODES + 255) / 256, 256, 0, stream>>>(deg, dinv, batch, cnt);

    if (use_wg) {
        wg_kernel<<<(ET + 255) / 256, 256, 0, stream>>>(ei, dinv, batch, we, ge);
        scatter_kernel<1><<<dim3(CHUNKS, NSLICE), 256, 0, stream>>>(x, ei, batch, dinv, we, ge, accg);
    } else {
        scatter_kernel<0><<<dim3(CHUNKS, NSLICE), 256, 0, stream>>>(x, ei, batch, dinv, we, ge, accg);
    }

    pooled_kernel<<<(N_GRAPH * DOUT + 255) / 256, 256, 0, stream>>>(accg, W, b, cnt, pooled);
    mlp_kernel<DOUT, HID, true><<<(N_GRAPH * HID + 255) / 256, 256, 0, stream>>>(pooled, W1, b1, z1);
    mlp_kernel<HID,  HID, true><<<(N_GRAPH * HID + 255) / 256, 256, 0, stream>>>(z1, W2, b2, z2);
    head_kernel<<<(N_GRAPH + 255) / 256, 256, 0, stream>>>(z2, Wc, bc, out);
}